// Round 9
// baseline (192.764 us; speedup 1.0000x reference)
//
#include <hip/hip_runtime.h>

#define KCODES 512
#define DDIM 64

typedef __attribute__((ext_vector_type(8))) short bf16x8;
typedef __attribute__((ext_vector_type(4))) float f32x4;

// ---- workspace layout (bytes) ----
#define WS_IMG    0          // 64 KB bf16-hi image [512][64], XOR-swizzled rows
#define WS_IMGLO  65536      // 64 KB bf16-lo image [512][64], UNSWIZZLED (read via L2)
#define WS_ESQB   131072     // f32[512] fl(esq + 0.5)  (biased, screening)
#define WS_ESQ    133120     // f32[512] raw np-pairwise esq (bit-exact rescore)
#define WS_MAXE   135168     // f32 max|e|
#define WS_CNTA   135172     // u32
#define WS_CNTB   135176     // u32
#define WS_LISTA  135184     // uint2[capA] {pix, (a<<9)|b} ; LISTB follows at +8*capA

__device__ __forceinline__ unsigned umin_(unsigned a, unsigned b) { return a < b ? a : b; }

// Split f32 into bf16 hi + bf16 lo (RNE). Verified rounds 3-5,7,8.
__device__ __forceinline__ void bf16_split(float v, unsigned short& hi, unsigned short& lo) {
    unsigned u = __float_as_uint(v);
    unsigned r = u + 0x7fffu + ((u >> 16) & 1u);
    hi = (unsigned short)(r >> 16);
    float hf = __uint_as_float(((unsigned)hi) << 16);
    float l = v - hf;
    unsigned u2 = __float_as_uint(l);
    unsigned r2 = u2 + 0x7fffu + ((u2 >> 16) & 1u);
    lo = (unsigned short)(r2 >> 16);
}

// Bit-exact emulation of the numpy-f32 reference distance (verified rounds 2-5,7,8):
//   z_sq: sequential ascending-d, pre-rounded squares; cross: sequential, mul+add no fma
//   dist = fl( fl(z_sq - fl(2*cross)) + esq )
__device__ __forceinline__ float np_dist_strided(const float* __restrict__ zp,
                                                 const float* __restrict__ e, float esqk) {
    float zq = 0.f, cr = 0.f;
    #pragma unroll 8
    for (int d = 0; d < DDIM; ++d) {
        float zv = zp[(size_t)d * 4096];
        zq = __fadd_rn(zq, __fmul_rn(zv, zv));
        cr = __fadd_rn(cr, __fmul_rn(zv, e[d]));
    }
    return __fadd_rn(__fsub_rn(zq, __fmul_rn(2.0f, cr)), esqk);
}

// ---------------- pre-kernel: tables + bf16 hi/lo image + counter zeroing ----------------
__global__ __launch_bounds__(512) void vq_pre_kernel(const float* __restrict__ emb,
                                                     char* __restrict__ ws)
{
    __shared__ float wmax[8];
    const int k = threadIdx.x;           // code 0..511
    const float* e = emb + k * DDIM;

    if (k == 0) { *(unsigned*)(ws + WS_CNTA) = 0u; *(unsigned*)(ws + WS_CNTB) = 0u; }

    // esq np-pairwise (contiguous-axis reduce: 8-accumulator pattern, verified round 2)
    float r[8];
    #pragma unroll
    for (int j = 0; j < 8; ++j) r[j] = __fmul_rn(e[j], e[j]);
    #pragma unroll
    for (int i = 8; i < DDIM; i += 8)
        #pragma unroll
        for (int j = 0; j < 8; ++j)
            r[j] = __fadd_rn(r[j], __fmul_rn(e[i + j], e[i + j]));
    float esq = __fadd_rn(
        __fadd_rn(__fadd_rn(r[0], r[1]), __fadd_rn(r[2], r[3])),
        __fadd_rn(__fadd_rn(r[4], r[5]), __fadd_rn(r[6], r[7])));
    ((float*)(ws + WS_ESQ))[k]  = esq;
    ((float*)(ws + WS_ESQB))[k] = __fadd_rn(esq, 0.5f);

    // hi: XOR-swizzled (row k, slot jidx -> k*64 + ((jidx^(k&7))*8)); lo: unswizzled
    unsigned short* ehi = (unsigned short*)(ws + WS_IMG);
    unsigned short* elo = (unsigned short*)(ws + WS_IMGLO);
    float me = 0.f;
    #pragma unroll
    for (int jidx = 0; jidx < 8; ++jidx) {
        bf16x8 hh, ll;
        #pragma unroll
        for (int j = 0; j < 8; ++j) {
            float v = e[jidx * 8 + j];
            me = fmaxf(me, fabsf(v));
            unsigned short h, l;
            bf16_split(v, h, l);
            hh[j] = (short)h; ll[j] = (short)l;
        }
        *(bf16x8*)&ehi[k * 64 + ((jidx ^ (k & 7)) << 3)] = hh;
        *(bf16x8*)&elo[k * 64 + (jidx << 3)]             = ll;
    }

    #pragma unroll
    for (int m = 1; m < 64; m <<= 1) me = fmaxf(me, __shfl_xor(me, m));
    if ((k & 63) == 0) wmax[k >> 6] = me;
    __syncthreads();
    if (k == 0) {
        float M = wmax[0];
        #pragma unroll
        for (int i = 1; i < 8; ++i) M = fmaxf(M, wmax[i]);
        *(float*)(ws + WS_MAXE) = M;
    }
}

// ---------------- main kernel: 512 threads, hi-in-LDS (67.6KB), lo-from-L2, 2 blocks/CU ----------------
__global__ __launch_bounds__(512, 4) void vq_main_kernel(
    const float* __restrict__ z, const float* __restrict__ emb,
    char* __restrict__ ws, int* __restrict__ out,
    unsigned capA, unsigned capB)
{
    __shared__ __align__(16) unsigned short simg[KCODES * DDIM];  // hi only, 64 KB
    __shared__ __align__(16) float esqb[KCODES];                  // 2 KB

    const int t    = threadIdx.x;
    const int lane = t & 63;
    const int w    = t >> 6;       // wave 0..7
    const int g    = lane >> 4;
    const int p16  = lane & 15;

    // stage hi image (once) + esqb
    {
        const float4* isrc = (const float4*)(ws + WS_IMG);
        float4* idst = (float4*)simg;
        #pragma unroll
        for (int i = 0; i < 8; ++i) idst[t + 512 * i] = isrc[t + 512 * i];
        esqb[t] = ((const float*)(ws + WS_ESQB))[t];
    }
    const float maxe = *((const float*)(ws + WS_MAXE));

    const int P0  = blockIdx.x * 512;
    const int bb  = P0 >> 12;
    const int hwW = (P0 & 4095) + w * 64;
    const float* zbase = z + (size_t)bb * (DDIM * 4096);

    // z fragments: 4 sets x 2 K-chunks, bf16 hi+lo; per-pixel partial sum|z|
    bf16x8 zh[4][2], zl[4][2];
    float  sab[4];
    #pragma unroll
    for (int s = 0; s < 4; ++s) {
        sab[s] = 0.f;
        #pragma unroll
        for (int c = 0; c < 2; ++c) {
            #pragma unroll
            for (int j = 0; j < 8; ++j) {
                int d = g * 8 + j + c * 32;
                float v = zbase[(size_t)d * 4096 + hwW + s * 16 + p16];
                sab[s] += fabsf(v);
                unsigned short h, l;
                bf16_split(v, h, l);
                zh[s][c][j] = (short)h;
                zl[s][c][j] = (short)l;
            }
        }
    }
    __syncthreads();

    const int jj0 = (g ^ (p16 & 7)) << 3;
    const int jj1 = (((4 + g) ^ (p16 & 7))) << 3;
    const int g4  = g * 4;
    const bf16x8* lob = (const bf16x8*)(ws + WS_IMGLO);   // unswizzled, L2-resident

    // top-3 positive-float sortable keys: bits(score)&~511 | code
    float m1[4], m2[4], m3[4];
    #pragma unroll
    for (int s = 0; s < 4; ++s) { m1[s] = m2[s] = m3[s] = 3.0e38f; }

    #pragma unroll 2
    for (int tt = 0; tt < 32; ++tt) {
        const int row = tt * 16 + p16;                 // row&7 == p16&7
        const bf16x8 ah0 = *(const bf16x8*)&simg[row * 64 + jj0];
        const bf16x8 ah1 = *(const bf16x8*)&simg[row * 64 + jj1];
        const bf16x8 al0 = lob[row * 8 + g];           // chunk0 cols g*8..g*8+7
        const bf16x8 al1 = lob[row * 8 + 4 + g];       // chunk1 cols 32+g*8..
        const f32x4 eq = *(const f32x4*)&esqb[tt * 16 + g4];
        const unsigned c0 = (unsigned)(tt * 16 + g4);

        #pragma unroll
        for (int s = 0; s < 4; ++s) {
            f32x4 acc = {0.f, 0.f, 0.f, 0.f};
            acc = __builtin_amdgcn_mfma_f32_16x16x32_bf16(ah0, zh[s][0], acc, 0, 0, 0);
            acc = __builtin_amdgcn_mfma_f32_16x16x32_bf16(ah1, zh[s][1], acc, 0, 0, 0);
            acc = __builtin_amdgcn_mfma_f32_16x16x32_bf16(al0, zh[s][0], acc, 0, 0, 0);
            acc = __builtin_amdgcn_mfma_f32_16x16x32_bf16(al1, zh[s][1], acc, 0, 0, 0);
            acc = __builtin_amdgcn_mfma_f32_16x16x32_bf16(ah0, zl[s][0], acc, 0, 0, 0);
            acc = __builtin_amdgcn_mfma_f32_16x16x32_bf16(ah1, zl[s][1], acc, 0, 0, 0);
            #pragma unroll
            for (int rr = 0; rr < 4; ++rr) {
                float sc = fmaf(-2.0f, acc[rr], eq[rr]);
                float kf = __uint_as_float(
                    (__float_as_uint(sc) & 0xFFFFFE00u) | (c0 + (unsigned)rr));
                // sorted top-3 insert; med3 valid since m1<=m2<=m3 invariant
                float n1 = fminf(kf, m1[s]);
                float n2 = __builtin_amdgcn_fmed3f(kf, m1[s], m2[s]);
                float n3 = __builtin_amdgcn_fmed3f(kf, m2[s], m3[s]);
                m1[s] = n1; m2[s] = n2; m3[s] = n3;
            }
        }
    }

    // merge the 4 code-partitions (lane groups) per set: butterfly xor 16, 32
    #pragma unroll
    for (int s = 0; s < 4; ++s) {
        #pragma unroll
        for (int st2 = 0; st2 < 2; ++st2) {
            const int mk = 16 << st2;
            float b1 = __shfl_xor(m1[s], mk);
            float b2 = __shfl_xor(m2[s], mk);
            float b3 = __shfl_xor(m3[s], mk);
            float osa = __shfl_xor(sab[s], mk);
            sab[s] += osa;
            float M1 = fminf(m1[s], b1), x = fmaxf(m1[s], b1);
            float c  = fminf(m2[s], b2), d = fmaxf(m2[s], b2);
            float M2 = fminf(x, c),      e2 = fmaxf(x, c);
            float M3 = fminf(fminf(e2, d), fminf(m3[s], b3));
            m1[s] = M1; m2[s] = M2; m3[s] = M3;
        }
    }

    // lane owns pixel (set=g, p16)
    float F1 = (g == 0) ? m1[0] : (g == 1) ? m1[1] : (g == 2) ? m1[2] : m1[3];
    float F2 = (g == 0) ? m2[0] : (g == 1) ? m2[1] : (g == 2) ? m2[2] : m2[3];
    float F3 = (g == 0) ? m3[0] : (g == 1) ? m3[1] : (g == 2) ? m3[2] : m3[3];
    float SA = (g == 0) ? sab[0] : (g == 1) ? sab[1] : (g == 2) ? sab[2] : sab[3];

    const unsigned K1 = __float_as_uint(F1);
    const unsigned K2 = __float_as_uint(F2);
    const unsigned K3 = __float_as_uint(F3);
    const float qs1 = __uint_as_float(K1 & 0xFFFFFE00u);
    const float qs2 = __uint_as_float(K2 & 0xFFFFFE00u);
    const float qs3 = __uint_as_float(K3 & 0xFFFFFE00u);
    const int   I1  = (int)(K1 & 511u);
    const int   I2  = (int)(K2 & 511u);

    // round-4/5/7/8-verified sound margin
    const float MARG = 6.0e-5f + 3.0e-5f * (SA * maxe);
    const bool  f2 = (qs2 - qs1) < MARG;
    const bool  f3 = ((qs3 - qs1) < MARG) || (2.f * SA * maxe > 0.45f) || !(qs1 > 0.f);

    const int pix = P0 + w * 64 + lane;
    bool ovf = false;
    if (f3) {
        unsigned i = atomicAdd((unsigned*)(ws + WS_CNTB), 1u);
        if (i < capB) ((unsigned*)(ws + WS_LISTA + 8ull * capA))[i] = (unsigned)pix;
        else ovf = true;
    } else if (f2) {
        unsigned i = atomicAdd((unsigned*)(ws + WS_CNTA), 1u);
        if (i < capA) {
            unsigned a = (unsigned)min(I1, I2), b = (unsigned)max(I1, I2);
            uint2 rec; rec.x = (unsigned)pix; rec.y = (a << 9) | b;
            ((uint2*)(ws + WS_LISTA))[i] = rec;
        } else ovf = true;
    }

    int idx = I1;
    // last-resort inline cooperative rescan (list overflow / caps==0 only)
    unsigned long long bal = __ballot(ovf);
    if (bal) {
        const float* esqr = (const float*)(ws + WS_ESQ);
        while (bal) {
            int pl = __ffsll((long long)bal) - 1;
            bal &= bal - 1;
            const float* zfp = zbase + hwW + pl;
            float bD = 3.0e38f; int bC = 0;
            #pragma unroll
            for (int j = 0; j < 8; ++j) {
                int c = j * 64 + lane;
                float D = np_dist_strided(zfp, emb + c * DDIM, esqr[c]);
                if (D < bD) { bD = D; bC = c; }
            }
            #pragma unroll
            for (int mk = 1; mk < 64; mk <<= 1) {
                float oD = __shfl_xor(bD, mk);
                int   oC = __shfl_xor(bC, mk);
                if (oD < bD || (oD == bD && oC < bC)) { bD = oD; bC = oC; }
            }
            if (lane == pl) idx = bC;
        }
    }
    out[pix] = idx;
}

// ---------------- tail kernel: resolve flagged pixels with bit-exact np semantics ----------------
__global__ __launch_bounds__(256) void vq_tail_kernel(
    const float* __restrict__ z, const float* __restrict__ emb,
    char* __restrict__ ws, int* __restrict__ out, unsigned capA, unsigned capB)
{
    const unsigned nA = umin_(*(const unsigned*)(ws + WS_CNTA), capA);
    const unsigned nB = umin_(*(const unsigned*)(ws + WS_CNTB), capB);
    const float* esqr = (const float*)(ws + WS_ESQ);
    const unsigned gid  = blockIdx.x * 256 + threadIdx.x;
    const unsigned gsz  = gridDim.x * 256;

    // type A: 2-candidate np compare, thread-parallel (a < b -> first-occurrence wins)
    for (unsigned i = gid; i < nA; i += gsz) {
        uint2 rec = ((const uint2*)(ws + WS_LISTA))[i];
        const int pix = (int)rec.x;
        const int a = (int)((rec.y >> 9) & 511u), b = (int)(rec.y & 511u);
        const float* zp = z + (size_t)(pix >> 12) * (DDIM * 4096) + (pix & 4095);
        float Da = np_dist_strided(zp, emb + a * DDIM, esqr[a]);
        float Db = np_dist_strided(zp, emb + b * DDIM, esqr[b]);
        out[pix] = (Db < Da) ? b : a;
    }

    // type B: full 512-code np rescan, wave-cooperative
    const unsigned wid  = gid >> 6;
    const unsigned nwav = gsz >> 6;
    const int lane = threadIdx.x & 63;
    const unsigned* listB = (const unsigned*)(ws + WS_LISTA + 8ull * capA);
    for (unsigned j = wid; j < nB; j += nwav) {
        const int pix = (int)listB[j];
        const float* zp = z + (size_t)(pix >> 12) * (DDIM * 4096) + (pix & 4095);
        float bD = 3.0e38f; int bC = 0;
        #pragma unroll
        for (int q = 0; q < 8; ++q) {
            int c = q * 64 + lane;
            float D = np_dist_strided(zp, emb + c * DDIM, esqr[c]);
            if (D < bD) { bD = D; bC = c; }
        }
        #pragma unroll
        for (int mk = 1; mk < 64; mk <<= 1) {
            float oD = __shfl_xor(bD, mk);
            int   oC = __shfl_xor(bC, mk);
            if (oD < bD || (oD == bD && oC < bC)) { bD = oD; bC = oC; }
        }
        if (lane == 0) out[pix] = bC;
    }
}

// ---------------- fallback (ws too small): round-2 verified self-contained kernel ----------------
__device__ __forceinline__ float fb_fast_score(const float4* __restrict__ e4,
                                               const float* zr, float esqk)
{
    float a0 = 0.f, a1 = 0.f, a2 = 0.f, a3 = 0.f;
    #pragma unroll
    for (int i = 0; i < DDIM / 4; ++i) {
        float4 v = e4[i];
        a0 = fmaf(zr[4*i+0], v.x, a0);
        a1 = fmaf(zr[4*i+1], v.y, a1);
        a2 = fmaf(zr[4*i+2], v.z, a2);
        a3 = fmaf(zr[4*i+3], v.w, a3);
    }
    return fmaf(-2.f, (a0 + a1) + (a2 + a3), esqk);
}

__device__ __forceinline__ float fb_np_dist(const float* __restrict__ e,
                                            const float* zr, float zsq, float esqk)
{
    float c = 0.f;
    #pragma unroll
    for (int d = 0; d < DDIM; ++d)
        c = __fadd_rn(c, __fmul_rn(zr[d], e[d]));
    return __fadd_rn(__fsub_rn(zsq, __fmul_rn(2.0f, c)), esqk);
}

__global__ __launch_bounds__(256) void vq_fallback_kernel(
    const float* __restrict__ z, const float* __restrict__ emb, int* __restrict__ out)
{
    __shared__ float esq[KCODES];
    const int t = threadIdx.x;
    for (int k = t; k < KCODES; k += 256) {
        const float* e = emb + k * DDIM;
        float r[8];
        #pragma unroll
        for (int j = 0; j < 8; ++j) r[j] = __fmul_rn(e[j], e[j]);
        #pragma unroll
        for (int i = 8; i < DDIM; i += 8)
            #pragma unroll
            for (int j = 0; j < 8; ++j)
                r[j] = __fadd_rn(r[j], __fmul_rn(e[i+j], e[i+j]));
        esq[k] = __fadd_rn(
            __fadd_rn(__fadd_rn(r[0], r[1]), __fadd_rn(r[2], r[3])),
            __fadd_rn(__fadd_rn(r[4], r[5]), __fadd_rn(r[6], r[7])));
    }
    __syncthreads();
    const int p  = blockIdx.x * 256 + t;
    const int b  = p >> 12;
    const int hw = p & 4095;
    const float* zp = z + (size_t)b * (DDIM * 4096) + hw;
    float zr[DDIM];
    #pragma unroll
    for (int d = 0; d < DDIM; ++d) zr[d] = zp[(size_t)d * 4096];
    float zsq = __fmul_rn(zr[0], zr[0]);
    #pragma unroll
    for (int d = 1; d < DDIM; ++d)
        zsq = __fadd_rn(zsq, __fmul_rn(zr[d], zr[d]));
    float m1 = 3.0e38f, m2 = 3.0e38f, m3 = 3.0e38f;
    int   i1 = 0, i2 = 0;
    for (int k = 0; k < KCODES; ++k) {
        const float s = fb_fast_score(reinterpret_cast<const float4*>(emb + k * DDIM), zr, esq[k]);
        const bool b1 = s < m1, b2 = s < m2, b3 = s < m3;
        const float nm3 = b2 ? m2 : (b3 ? s : m3);
        const float nm2 = b1 ? m1 : (b2 ? s : m2);
        const int   ni2 = b1 ? i1 : (b2 ? k : i2);
        const float nm1 = b1 ? s : m1;
        const int   ni1 = b1 ? k : i1;
        m3 = nm3; m2 = nm2; i2 = ni2; m1 = nm1; i1 = ni1;
    }
    int idx = i1;
    if (m2 - m1 < 6.0e-5f) {
        if (m3 - m1 >= 6.0e-5f) {
            const float D1 = fb_np_dist(emb + i1 * DDIM, zr, zsq, esq[i1]);
            const float D2 = fb_np_dist(emb + i2 * DDIM, zr, zsq, esq[i2]);
            const int   ka = (i1 < i2) ? i1 : i2;
            const int   kb = (i1 < i2) ? i2 : i1;
            const float Da = (i1 < i2) ? D1 : D2;
            const float Db = (i1 < i2) ? D2 : D1;
            idx = (Db < Da) ? kb : ka;
        } else {
            float bestD = 3.0e38f; int bi = 0; bool found = false;
            for (int k = 0; k < KCODES; ++k) {
                const float s = fb_fast_score(reinterpret_cast<const float4*>(emb + k * DDIM), zr, esq[k]);
                if (s < m1 + 6.0e-5f) {
                    const float Dk = fb_np_dist(emb + k * DDIM, zr, zsq, esq[k]);
                    if (!found || Dk < bestD) { bestD = Dk; bi = k; found = true; }
                }
            }
            idx = bi;
        }
    }
    out[p] = idx;
}

extern "C" void kernel_launch(void* const* d_in, const int* in_sizes, int n_in,
                              void* d_out, int out_size, void* d_ws, size_t ws_size,
                              hipStream_t stream)
{
    const float* z   = (const float*)d_in[0];
    const float* emb = (const float*)d_in[1];
    int* out = (int*)d_out;

    // pick list capacities from available workspace
    unsigned capA = 0, capB = 0;
    if (ws_size >= (size_t)WS_LISTA + 32768ull * 8 + 8192ull * 4)      { capA = 32768; capB = 8192; }
    else if (ws_size >= (size_t)WS_LISTA + 16384ull * 8 + 4096ull * 4) { capA = 16384; capB = 4096; }

    if (ws_size >= (size_t)WS_LISTA && (out_size % 512) == 0) {
        hipLaunchKernelGGL(vq_pre_kernel, dim3(1), dim3(512), 0, stream, emb, (char*)d_ws);
        hipLaunchKernelGGL(vq_main_kernel, dim3(out_size / 512), dim3(512), 0, stream,
                           z, emb, (char*)d_ws, out, capA, capB);
        if (capA > 0)
            hipLaunchKernelGGL(vq_tail_kernel, dim3(128), dim3(256), 0, stream,
                               z, emb, (char*)d_ws, out, capA, capB);
    } else {
        hipLaunchKernelGGL(vq_fallback_kernel, dim3((out_size + 255) / 256), dim3(256), 0, stream,
                           z, emb, out);
    }
}

// Round 10
// 156.035 us; speedup vs baseline: 1.2354x; 1.2354x over previous
//
#include <hip/hip_runtime.h>

#define KCODES 512
#define DDIM 64

typedef __attribute__((ext_vector_type(8))) short bf16x8;
typedef __attribute__((ext_vector_type(4))) float f32x4;

// ---- workspace layout (bytes) ----
#define WS_IMG    0          // 64 KB bf16-hi image [512][64], XOR-swizzled rows
#define WS_IMGLO  65536      // 64 KB bf16-lo image [512][64], UNSWIZZLED (read via L2)
#define WS_ESQB   131072     // f32[512] fl(esq + 0.5)  (biased, screening)
#define WS_ESQ    133120     // f32[512] raw np-pairwise esq (bit-exact rescore)
#define WS_MAXE   135168     // f32 max|e|
#define WS_CNTA   135172     // u32
#define WS_CNTB   135176     // u32
#define WS_LISTA  135184     // uint2[capA] {pix, (a<<9)|b} ; LISTB follows at +8*capA

__device__ __forceinline__ unsigned umin_(unsigned a, unsigned b) { return a < b ? a : b; }

// Split f32 into bf16 hi + bf16 lo (RNE). Verified rounds 3-5,7,8.
__device__ __forceinline__ void bf16_split(float v, unsigned short& hi, unsigned short& lo) {
    unsigned u = __float_as_uint(v);
    unsigned r = u + 0x7fffu + ((u >> 16) & 1u);
    hi = (unsigned short)(r >> 16);
    float hf = __uint_as_float(((unsigned)hi) << 16);
    float l = v - hf;
    unsigned u2 = __float_as_uint(l);
    unsigned r2 = u2 + 0x7fffu + ((u2 >> 16) & 1u);
    lo = (unsigned short)(r2 >> 16);
}

// Bit-exact emulation of the numpy-f32 reference distance (verified rounds 2-5,7,8):
//   z_sq: sequential ascending-d, pre-rounded squares; cross: sequential, mul+add no fma
//   dist = fl( fl(z_sq - fl(2*cross)) + esq )
__device__ __forceinline__ float np_dist_strided(const float* __restrict__ zp,
                                                 const float* __restrict__ e, float esqk) {
    float zq = 0.f, cr = 0.f;
    #pragma unroll 8
    for (int d = 0; d < DDIM; ++d) {
        float zv = zp[(size_t)d * 4096];
        zq = __fadd_rn(zq, __fmul_rn(zv, zv));
        cr = __fadd_rn(cr, __fmul_rn(zv, e[d]));
    }
    return __fadd_rn(__fsub_rn(zq, __fmul_rn(2.0f, cr)), esqk);
}

// ---------------- pre-kernel: tables + bf16 hi/lo image + counter zeroing ----------------
__global__ __launch_bounds__(512) void vq_pre_kernel(const float* __restrict__ emb,
                                                     char* __restrict__ ws)
{
    __shared__ float wmax[8];
    const int k = threadIdx.x;           // code 0..511
    const float* e = emb + k * DDIM;

    if (k == 0) { *(unsigned*)(ws + WS_CNTA) = 0u; *(unsigned*)(ws + WS_CNTB) = 0u; }

    // esq np-pairwise (contiguous-axis reduce: 8-accumulator pattern, verified round 2)
    float r[8];
    #pragma unroll
    for (int j = 0; j < 8; ++j) r[j] = __fmul_rn(e[j], e[j]);
    #pragma unroll
    for (int i = 8; i < DDIM; i += 8)
        #pragma unroll
        for (int j = 0; j < 8; ++j)
            r[j] = __fadd_rn(r[j], __fmul_rn(e[i + j], e[i + j]));
    float esq = __fadd_rn(
        __fadd_rn(__fadd_rn(r[0], r[1]), __fadd_rn(r[2], r[3])),
        __fadd_rn(__fadd_rn(r[4], r[5]), __fadd_rn(r[6], r[7])));
    ((float*)(ws + WS_ESQ))[k]  = esq;
    ((float*)(ws + WS_ESQB))[k] = __fadd_rn(esq, 0.5f);

    // hi: XOR-swizzled (row k, slot jidx -> k*64 + ((jidx^(k&7))*8)); lo: unswizzled
    unsigned short* ehi = (unsigned short*)(ws + WS_IMG);
    unsigned short* elo = (unsigned short*)(ws + WS_IMGLO);
    float me = 0.f;
    #pragma unroll
    for (int jidx = 0; jidx < 8; ++jidx) {
        bf16x8 hh, ll;
        #pragma unroll
        for (int j = 0; j < 8; ++j) {
            float v = e[jidx * 8 + j];
            me = fmaxf(me, fabsf(v));
            unsigned short h, l;
            bf16_split(v, h, l);
            hh[j] = (short)h; ll[j] = (short)l;
        }
        *(bf16x8*)&ehi[k * 64 + ((jidx ^ (k & 7)) << 3)] = hh;
        *(bf16x8*)&elo[k * 64 + (jidx << 3)]             = ll;
    }

    #pragma unroll
    for (int m = 1; m < 64; m <<= 1) me = fmaxf(me, __shfl_xor(me, m));
    if ((k & 63) == 0) wmax[k >> 6] = me;
    __syncthreads();
    if (k == 0) {
        float M = wmax[0];
        #pragma unroll
        for (int i = 1; i < 8; ++i) M = fmaxf(M, wmax[i]);
        *(float*)(ws + WS_MAXE) = M;
    }
}

// ---------------- main kernel: 512 threads, hi-in-LDS (67.6KB), lo-from-L2 ----------------
// NO min-waves arg: r5/r9 showed an explicit cap triggers 64-VGPR allocation + spills.
// r8 evidence: this body allocates ~128 VGPR naturally = the 4-waves/SIMD boundary.
__global__ __launch_bounds__(512) void vq_main_kernel(
    const float* __restrict__ z, const float* __restrict__ emb,
    char* __restrict__ ws, int* __restrict__ out,
    unsigned capA, unsigned capB)
{
    __shared__ __align__(16) unsigned short simg[KCODES * DDIM];  // hi only, 64 KB
    __shared__ __align__(16) float esqb[KCODES];                  // 2 KB

    const int t    = threadIdx.x;
    const int lane = t & 63;
    const int w    = t >> 6;       // wave 0..7
    const int g    = lane >> 4;
    const int p16  = lane & 15;

    // stage hi image (once) + esqb
    {
        const float4* isrc = (const float4*)(ws + WS_IMG);
        float4* idst = (float4*)simg;
        #pragma unroll
        for (int i = 0; i < 8; ++i) idst[t + 512 * i] = isrc[t + 512 * i];
        esqb[t] = ((const float*)(ws + WS_ESQB))[t];
    }
    const float maxe = *((const float*)(ws + WS_MAXE));

    const int P0  = blockIdx.x * 512;
    const int bb  = P0 >> 12;
    const int hwW = (P0 & 4095) + w * 64;
    const float* zbase = z + (size_t)bb * (DDIM * 4096);

    // z fragments: 4 sets x 2 K-chunks, bf16 hi+lo; per-pixel partial sum|z|
    bf16x8 zh[4][2], zl[4][2];
    float  sab[4];
    #pragma unroll
    for (int s = 0; s < 4; ++s) {
        sab[s] = 0.f;
        #pragma unroll
        for (int c = 0; c < 2; ++c) {
            #pragma unroll
            for (int j = 0; j < 8; ++j) {
                int d = g * 8 + j + c * 32;
                float v = zbase[(size_t)d * 4096 + hwW + s * 16 + p16];
                sab[s] += fabsf(v);
                unsigned short h, l;
                bf16_split(v, h, l);
                zh[s][c][j] = (short)h;
                zl[s][c][j] = (short)l;
            }
        }
    }
    __syncthreads();

    const int jj0 = (g ^ (p16 & 7)) << 3;
    const int jj1 = (((4 + g) ^ (p16 & 7))) << 3;
    const int g4  = g * 4;
    const bf16x8* lob = (const bf16x8*)(ws + WS_IMGLO);   // unswizzled, L2-resident

    // top-3 positive-float sortable keys: bits(score)&~511 | code
    float m1[4], m2[4], m3[4];
    #pragma unroll
    for (int s = 0; s < 4; ++s) { m1[s] = m2[s] = m3[s] = 3.0e38f; }

    #pragma unroll 2
    for (int tt = 0; tt < 32; ++tt) {
        const int row = tt * 16 + p16;                 // row&7 == p16&7
        const bf16x8 ah0 = *(const bf16x8*)&simg[row * 64 + jj0];
        const bf16x8 ah1 = *(const bf16x8*)&simg[row * 64 + jj1];
        const bf16x8 al0 = lob[row * 8 + g];           // chunk0 cols g*8..g*8+7
        const bf16x8 al1 = lob[row * 8 + 4 + g];       // chunk1 cols 32+g*8..
        const f32x4 eq = *(const f32x4*)&esqb[tt * 16 + g4];
        const unsigned c0 = (unsigned)(tt * 16 + g4);

        #pragma unroll
        for (int s = 0; s < 4; ++s) {
            f32x4 acc = {0.f, 0.f, 0.f, 0.f};
            acc = __builtin_amdgcn_mfma_f32_16x16x32_bf16(ah0, zh[s][0], acc, 0, 0, 0);
            acc = __builtin_amdgcn_mfma_f32_16x16x32_bf16(ah1, zh[s][1], acc, 0, 0, 0);
            acc = __builtin_amdgcn_mfma_f32_16x16x32_bf16(al0, zh[s][0], acc, 0, 0, 0);
            acc = __builtin_amdgcn_mfma_f32_16x16x32_bf16(al1, zh[s][1], acc, 0, 0, 0);
            acc = __builtin_amdgcn_mfma_f32_16x16x32_bf16(ah0, zl[s][0], acc, 0, 0, 0);
            acc = __builtin_amdgcn_mfma_f32_16x16x32_bf16(ah1, zl[s][1], acc, 0, 0, 0);
            #pragma unroll
            for (int rr = 0; rr < 4; ++rr) {
                float sc = fmaf(-2.0f, acc[rr], eq[rr]);
                float kf = __uint_as_float(
                    (__float_as_uint(sc) & 0xFFFFFE00u) | (c0 + (unsigned)rr));
                // sorted top-3 insert; med3 valid since m1<=m2<=m3 invariant
                float n1 = fminf(kf, m1[s]);
                float n2 = __builtin_amdgcn_fmed3f(kf, m1[s], m2[s]);
                float n3 = __builtin_amdgcn_fmed3f(kf, m2[s], m3[s]);
                m1[s] = n1; m2[s] = n2; m3[s] = n3;
            }
        }
    }

    // merge the 4 code-partitions (lane groups) per set: butterfly xor 16, 32
    #pragma unroll
    for (int s = 0; s < 4; ++s) {
        #pragma unroll
        for (int st2 = 0; st2 < 2; ++st2) {
            const int mk = 16 << st2;
            float b1 = __shfl_xor(m1[s], mk);
            float b2 = __shfl_xor(m2[s], mk);
            float b3 = __shfl_xor(m3[s], mk);
            float osa = __shfl_xor(sab[s], mk);
            sab[s] += osa;
            float M1 = fminf(m1[s], b1), x = fmaxf(m1[s], b1);
            float c  = fminf(m2[s], b2), d = fmaxf(m2[s], b2);
            float M2 = fminf(x, c),      e2 = fmaxf(x, c);
            float M3 = fminf(fminf(e2, d), fminf(m3[s], b3));
            m1[s] = M1; m2[s] = M2; m3[s] = M3;
        }
    }

    // lane owns pixel (set=g, p16)
    float F1 = (g == 0) ? m1[0] : (g == 1) ? m1[1] : (g == 2) ? m1[2] : m1[3];
    float F2 = (g == 0) ? m2[0] : (g == 1) ? m2[1] : (g == 2) ? m2[2] : m2[3];
    float F3 = (g == 0) ? m3[0] : (g == 1) ? m3[1] : (g == 2) ? m3[2] : m3[3];
    float SA = (g == 0) ? sab[0] : (g == 1) ? sab[1] : (g == 2) ? sab[2] : sab[3];

    const unsigned K1 = __float_as_uint(F1);
    const unsigned K2 = __float_as_uint(F2);
    const unsigned K3 = __float_as_uint(F3);
    const float qs1 = __uint_as_float(K1 & 0xFFFFFE00u);
    const float qs2 = __uint_as_float(K2 & 0xFFFFFE00u);
    const float qs3 = __uint_as_float(K3 & 0xFFFFFE00u);
    const int   I1  = (int)(K1 & 511u);
    const int   I2  = (int)(K2 & 511u);

    // round-4/5/7/8-verified sound margin
    const float MARG = 6.0e-5f + 3.0e-5f * (SA * maxe);
    const bool  f2 = (qs2 - qs1) < MARG;
    const bool  f3 = ((qs3 - qs1) < MARG) || (2.f * SA * maxe > 0.45f) || !(qs1 > 0.f);

    const int pix = P0 + w * 64 + lane;
    bool ovf = false;
    if (f3) {
        unsigned i = atomicAdd((unsigned*)(ws + WS_CNTB), 1u);
        if (i < capB) ((unsigned*)(ws + WS_LISTA + 8ull * capA))[i] = (unsigned)pix;
        else ovf = true;
    } else if (f2) {
        unsigned i = atomicAdd((unsigned*)(ws + WS_CNTA), 1u);
        if (i < capA) {
            unsigned a = (unsigned)min(I1, I2), b = (unsigned)max(I1, I2);
            uint2 rec; rec.x = (unsigned)pix; rec.y = (a << 9) | b;
            ((uint2*)(ws + WS_LISTA))[i] = rec;
        } else ovf = true;
    }

    int idx = I1;
    // last-resort inline cooperative rescan (list overflow / caps==0 only)
    unsigned long long bal = __ballot(ovf);
    if (bal) {
        const float* esqr = (const float*)(ws + WS_ESQ);
        while (bal) {
            int pl = __ffsll((long long)bal) - 1;
            bal &= bal - 1;
            const float* zfp = zbase + hwW + pl;
            float bD = 3.0e38f; int bC = 0;
            #pragma unroll
            for (int j = 0; j < 8; ++j) {
                int c = j * 64 + lane;
                float D = np_dist_strided(zfp, emb + c * DDIM, esqr[c]);
                if (D < bD) { bD = D; bC = c; }
            }
            #pragma unroll
            for (int mk = 1; mk < 64; mk <<= 1) {
                float oD = __shfl_xor(bD, mk);
                int   oC = __shfl_xor(bC, mk);
                if (oD < bD || (oD == bD && oC < bC)) { bD = oD; bC = oC; }
            }
            if (lane == pl) idx = bC;
        }
    }
    out[pix] = idx;
}

// ---------------- tail kernel: resolve flagged pixels with bit-exact np semantics ----------------
__global__ __launch_bounds__(256) void vq_tail_kernel(
    const float* __restrict__ z, const float* __restrict__ emb,
    char* __restrict__ ws, int* __restrict__ out, unsigned capA, unsigned capB)
{
    const unsigned nA = umin_(*(const unsigned*)(ws + WS_CNTA), capA);
    const unsigned nB = umin_(*(const unsigned*)(ws + WS_CNTB), capB);
    const float* esqr = (const float*)(ws + WS_ESQ);
    const unsigned gid  = blockIdx.x * 256 + threadIdx.x;
    const unsigned gsz  = gridDim.x * 256;

    // type A: 2-candidate np compare, thread-parallel (a < b -> first-occurrence wins)
    for (unsigned i = gid; i < nA; i += gsz) {
        uint2 rec = ((const uint2*)(ws + WS_LISTA))[i];
        const int pix = (int)rec.x;
        const int a = (int)((rec.y >> 9) & 511u), b = (int)(rec.y & 511u);
        const float* zp = z + (size_t)(pix >> 12) * (DDIM * 4096) + (pix & 4095);
        float Da = np_dist_strided(zp, emb + a * DDIM, esqr[a]);
        float Db = np_dist_strided(zp, emb + b * DDIM, esqr[b]);
        out[pix] = (Db < Da) ? b : a;
    }

    // type B: full 512-code np rescan, wave-cooperative
    const unsigned wid  = gid >> 6;
    const unsigned nwav = gsz >> 6;
    const int lane = threadIdx.x & 63;
    const unsigned* listB = (const unsigned*)(ws + WS_LISTA + 8ull * capA);
    for (unsigned j = wid; j < nB; j += nwav) {
        const int pix = (int)listB[j];
        const float* zp = z + (size_t)(pix >> 12) * (DDIM * 4096) + (pix & 4095);
        float bD = 3.0e38f; int bC = 0;
        #pragma unroll
        for (int q = 0; q < 8; ++q) {
            int c = q * 64 + lane;
            float D = np_dist_strided(zp, emb + c * DDIM, esqr[c]);
            if (D < bD) { bD = D; bC = c; }
        }
        #pragma unroll
        for (int mk = 1; mk < 64; mk <<= 1) {
            float oD = __shfl_xor(bD, mk);
            int   oC = __shfl_xor(bC, mk);
            if (oD < bD || (oD == bD && oC < bC)) { bD = oD; bC = oC; }
        }
        if (lane == 0) out[pix] = bC;
    }
}

// ---------------- fallback (ws too small): round-2 verified self-contained kernel ----------------
__device__ __forceinline__ float fb_fast_score(const float4* __restrict__ e4,
                                               const float* zr, float esqk)
{
    float a0 = 0.f, a1 = 0.f, a2 = 0.f, a3 = 0.f;
    #pragma unroll
    for (int i = 0; i < DDIM / 4; ++i) {
        float4 v = e4[i];
        a0 = fmaf(zr[4*i+0], v.x, a0);
        a1 = fmaf(zr[4*i+1], v.y, a1);
        a2 = fmaf(zr[4*i+2], v.z, a2);
        a3 = fmaf(zr[4*i+3], v.w, a3);
    }
    return fmaf(-2.f, (a0 + a1) + (a2 + a3), esqk);
}

__device__ __forceinline__ float fb_np_dist(const float* __restrict__ e,
                                            const float* zr, float zsq, float esqk)
{
    float c = 0.f;
    #pragma unroll
    for (int d = 0; d < DDIM; ++d)
        c = __fadd_rn(c, __fmul_rn(zr[d], e[d]));
    return __fadd_rn(__fsub_rn(zsq, __fmul_rn(2.0f, c)), esqk);
}

__global__ __launch_bounds__(256) void vq_fallback_kernel(
    const float* __restrict__ z, const float* __restrict__ emb, int* __restrict__ out)
{
    __shared__ float esq[KCODES];
    const int t = threadIdx.x;
    for (int k = t; k < KCODES; k += 256) {
        const float* e = emb + k * DDIM;
        float r[8];
        #pragma unroll
        for (int j = 0; j < 8; ++j) r[j] = __fmul_rn(e[j], e[j]);
        #pragma unroll
        for (int i = 8; i < DDIM; i += 8)
            #pragma unroll
            for (int j = 0; j < 8; ++j)
                r[j] = __fadd_rn(r[j], __fmul_rn(e[i+j], e[i+j]));
        esq[k] = __fadd_rn(
            __fadd_rn(__fadd_rn(r[0], r[1]), __fadd_rn(r[2], r[3])),
            __fadd_rn(__fadd_rn(r[4], r[5]), __fadd_rn(r[6], r[7])));
    }
    __syncthreads();
    const int p  = blockIdx.x * 256 + t;
    const int b  = p >> 12;
    const int hw = p & 4095;
    const float* zp = z + (size_t)b * (DDIM * 4096) + hw;
    float zr[DDIM];
    #pragma unroll
    for (int d = 0; d < DDIM; ++d) zr[d] = zp[(size_t)d * 4096];
    float zsq = __fmul_rn(zr[0], zr[0]);
    #pragma unroll
    for (int d = 1; d < DDIM; ++d)
        zsq = __fadd_rn(zsq, __fmul_rn(zr[d], zr[d]));
    float m1 = 3.0e38f, m2 = 3.0e38f, m3 = 3.0e38f;
    int   i1 = 0, i2 = 0;
    for (int k = 0; k < KCODES; ++k) {
        const float s = fb_fast_score(reinterpret_cast<const float4*>(emb + k * DDIM), zr, esq[k]);
        const bool b1 = s < m1, b2 = s < m2, b3 = s < m3;
        const float nm3 = b2 ? m2 : (b3 ? s : m3);
        const float nm2 = b1 ? m1 : (b2 ? s : m2);
        const int   ni2 = b1 ? i1 : (b2 ? k : i2);
        const float nm1 = b1 ? s : m1;
        const int   ni1 = b1 ? k : i1;
        m3 = nm3; m2 = nm2; i2 = ni2; m1 = nm1; i1 = ni1;
    }
    int idx = i1;
    if (m2 - m1 < 6.0e-5f) {
        if (m3 - m1 >= 6.0e-5f) {
            const float D1 = fb_np_dist(emb + i1 * DDIM, zr, zsq, esq[i1]);
            const float D2 = fb_np_dist(emb + i2 * DDIM, zr, zsq, esq[i2]);
            const int   ka = (i1 < i2) ? i1 : i2;
            const int   kb = (i1 < i2) ? i2 : i1;
            const float Da = (i1 < i2) ? D1 : D2;
            const float Db = (i1 < i2) ? D2 : D1;
            idx = (Db < Da) ? kb : ka;
        } else {
            float bestD = 3.0e38f; int bi = 0; bool found = false;
            for (int k = 0; k < KCODES; ++k) {
                const float s = fb_fast_score(reinterpret_cast<const float4*>(emb + k * DDIM), zr, esq[k]);
                if (s < m1 + 6.0e-5f) {
                    const float Dk = fb_np_dist(emb + k * DDIM, zr, zsq, esq[k]);
                    if (!found || Dk < bestD) { bestD = Dk; bi = k; found = true; }
                }
            }
            idx = bi;
        }
    }
    out[p] = idx;
}

extern "C" void kernel_launch(void* const* d_in, const int* in_sizes, int n_in,
                              void* d_out, int out_size, void* d_ws, size_t ws_size,
                              hipStream_t stream)
{
    const float* z   = (const float*)d_in[0];
    const float* emb = (const float*)d_in[1];
    int* out = (int*)d_out;

    // pick list capacities from available workspace
    unsigned capA = 0, capB = 0;
    if (ws_size >= (size_t)WS_LISTA + 32768ull * 8 + 8192ull * 4)      { capA = 32768; capB = 8192; }
    else if (ws_size >= (size_t)WS_LISTA + 16384ull * 8 + 4096ull * 4) { capA = 16384; capB = 4096; }

    if (ws_size >= (size_t)WS_LISTA && (out_size % 512) == 0) {
        hipLaunchKernelGGL(vq_pre_kernel, dim3(1), dim3(512), 0, stream, emb, (char*)d_ws);
        hipLaunchKernelGGL(vq_main_kernel, dim3(out_size / 512), dim3(512), 0, stream,
                           z, emb, (char*)d_ws, out, capA, capB);
        if (capA > 0)
            hipLaunchKernelGGL(vq_tail_kernel, dim3(128), dim3(256), 0, stream,
                               z, emb, (char*)d_ws, out, capA, capB);
    } else {
        hipLaunchKernelGGL(vq_fallback_kernel, dim3((out_size + 255) / 256), dim3(256), 0, stream,
                           z, emb, out);
    }
}

// Round 11
// 147.894 us; speedup vs baseline: 1.3034x; 1.0550x over previous
//
#include <hip/hip_runtime.h>

#define KCODES 512
#define DDIM 64

typedef __attribute__((ext_vector_type(8))) short bf16x8;
typedef __attribute__((ext_vector_type(4))) float f32x4;

// ---- workspace layout (bytes) ----
#define WS_IMG    0          // 64 KB bf16-hi image [512][64], XOR-swizzled rows
#define WS_IMGLO  65536      // 64 KB bf16-lo image [512][64], UNSWIZZLED (read via L2)
#define WS_ESQB   131072     // f32[512] fl(esq + 0.5)  (biased, screening; read from L2)
#define WS_ESQ    133120     // f32[512] raw np-pairwise esq (bit-exact rescore)
#define WS_MAXE8  135168     // f32[8]  per-pre-block max|e| slots
#define WS_CNTA   135200     // u32
#define WS_CNTB   135204     // u32
#define WS_LISTA  135208     // uint2[capA] {pix, (a<<9)|b} ; LISTB follows at +8*capA

__device__ __forceinline__ unsigned umin_(unsigned a, unsigned b) { return a < b ? a : b; }

// Split f32 into bf16 hi + bf16 lo (RNE). Verified rounds 3-5,7,8,10.
__device__ __forceinline__ void bf16_split(float v, unsigned short& hi, unsigned short& lo) {
    unsigned u = __float_as_uint(v);
    unsigned r = u + 0x7fffu + ((u >> 16) & 1u);
    hi = (unsigned short)(r >> 16);
    float hf = __uint_as_float(((unsigned)hi) << 16);
    float l = v - hf;
    unsigned u2 = __float_as_uint(l);
    unsigned r2 = u2 + 0x7fffu + ((u2 >> 16) & 1u);
    lo = (unsigned short)(r2 >> 16);
}

// Bit-exact emulation of the numpy-f32 reference distance (verified rounds 2-5,7,8,10):
//   z_sq: sequential ascending-d, pre-rounded squares; cross: sequential, mul+add no fma
//   dist = fl( fl(z_sq - fl(2*cross)) + esq )
__device__ __forceinline__ float np_dist_strided(const float* __restrict__ zp,
                                                 const float* __restrict__ e, float esqk) {
    float zq = 0.f, cr = 0.f;
    #pragma unroll 8
    for (int d = 0; d < DDIM; ++d) {
        float zv = zp[(size_t)d * 4096];
        zq = __fadd_rn(zq, __fmul_rn(zv, zv));
        cr = __fadd_rn(cr, __fmul_rn(zv, e[d]));
    }
    return __fadd_rn(__fsub_rn(zq, __fmul_rn(2.0f, cr)), esqk);
}

// ---------------- pre-kernel: 8 blocks x 64 threads (1 code/thread, 1 wave/block) ----------------
__global__ __launch_bounds__(64) void vq_pre_kernel(const float* __restrict__ emb,
                                                    char* __restrict__ ws)
{
    const int k = blockIdx.x * 64 + threadIdx.x;   // code 0..511
    const float* e = emb + k * DDIM;

    if (blockIdx.x == 0 && threadIdx.x == 0) {
        *(unsigned*)(ws + WS_CNTA) = 0u;
        *(unsigned*)(ws + WS_CNTB) = 0u;
    }

    // esq np-pairwise (contiguous-axis reduce: 8-accumulator pattern, verified round 2)
    float r[8];
    #pragma unroll
    for (int j = 0; j < 8; ++j) r[j] = __fmul_rn(e[j], e[j]);
    #pragma unroll
    for (int i = 8; i < DDIM; i += 8)
        #pragma unroll
        for (int j = 0; j < 8; ++j)
            r[j] = __fadd_rn(r[j], __fmul_rn(e[i + j], e[i + j]));
    float esq = __fadd_rn(
        __fadd_rn(__fadd_rn(r[0], r[1]), __fadd_rn(r[2], r[3])),
        __fadd_rn(__fadd_rn(r[4], r[5]), __fadd_rn(r[6], r[7])));
    ((float*)(ws + WS_ESQ))[k]  = esq;
    ((float*)(ws + WS_ESQB))[k] = __fadd_rn(esq, 0.5f);

    // hi: XOR-swizzled (row k, slot jidx -> k*64 + ((jidx^(k&7))*8)); lo: unswizzled
    unsigned short* ehi = (unsigned short*)(ws + WS_IMG);
    unsigned short* elo = (unsigned short*)(ws + WS_IMGLO);
    float me = 0.f;
    #pragma unroll
    for (int jidx = 0; jidx < 8; ++jidx) {
        bf16x8 hh, ll;
        #pragma unroll
        for (int j = 0; j < 8; ++j) {
            float v = e[jidx * 8 + j];
            me = fmaxf(me, fabsf(v));
            unsigned short h, l;
            bf16_split(v, h, l);
            hh[j] = (short)h; ll[j] = (short)l;
        }
        *(bf16x8*)&ehi[k * 64 + ((jidx ^ (k & 7)) << 3)] = hh;
        *(bf16x8*)&elo[k * 64 + (jidx << 3)]             = ll;
    }

    // per-block (one wave) max reduce -> own slot; main kernel reduces the 8 slots
    #pragma unroll
    for (int m = 1; m < 64; m <<= 1) me = fmaxf(me, __shfl_xor(me, m));
    if (threadIdx.x == 0) ((float*)(ws + WS_MAXE8))[blockIdx.x] = me;
}

// ---------------- main kernel: 512 threads, hi-in-LDS (exactly 64KB), lo+esqb from L2 ----------------
// NO min-waves arg (r5/r9: explicit cap => 64-VGPR spills). LDS = 65536 B exactly:
// m132 precedent says 64KB LDS co-schedules 2 blocks/CU on gfx950; 67.6KB (r10) did not.
__global__ __launch_bounds__(512) void vq_main_kernel(
    const float* __restrict__ z, const float* __restrict__ emb,
    char* __restrict__ ws, int* __restrict__ out,
    unsigned capA, unsigned capB)
{
    __shared__ __align__(16) unsigned short simg[KCODES * DDIM];  // hi only, 64 KB exactly

    const int t    = threadIdx.x;
    const int lane = t & 63;
    const int w    = t >> 6;       // wave 0..7
    const int g    = lane >> 4;
    const int p16  = lane & 15;

    // stage hi image (once)
    {
        const float4* isrc = (const float4*)(ws + WS_IMG);
        float4* idst = (float4*)simg;
        #pragma unroll
        for (int i = 0; i < 8; ++i) idst[t + 512 * i] = isrc[t + 512 * i];
    }
    // max|e| from the 8 pre-block slots
    float maxe = ((const float*)(ws + WS_MAXE8))[0];
    #pragma unroll
    for (int i = 1; i < 8; ++i) maxe = fmaxf(maxe, ((const float*)(ws + WS_MAXE8))[i]);

    const int P0  = blockIdx.x * 512;
    const int bb  = P0 >> 12;
    const int hwW = (P0 & 4095) + w * 64;
    const float* zbase = z + (size_t)bb * (DDIM * 4096);

    // z fragments: 4 sets x 2 K-chunks, bf16 hi+lo; per-pixel partial sum|z|
    bf16x8 zh[4][2], zl[4][2];
    float  sab[4];
    #pragma unroll
    for (int s = 0; s < 4; ++s) {
        sab[s] = 0.f;
        #pragma unroll
        for (int c = 0; c < 2; ++c) {
            #pragma unroll
            for (int j = 0; j < 8; ++j) {
                int d = g * 8 + j + c * 32;
                float v = zbase[(size_t)d * 4096 + hwW + s * 16 + p16];
                sab[s] += fabsf(v);
                unsigned short h, l;
                bf16_split(v, h, l);
                zh[s][c][j] = (short)h;
                zl[s][c][j] = (short)l;
            }
        }
    }
    __syncthreads();

    const int jj0 = (g ^ (p16 & 7)) << 3;
    const int jj1 = (((4 + g) ^ (p16 & 7))) << 3;
    const bf16x8* lob = (const bf16x8*)(ws + WS_IMGLO);   // unswizzled, L2-resident
    const f32x4*  eqb = (const f32x4*)(ws + WS_ESQB);     // 2KB table, L2-resident

    // top-3 positive-float sortable keys: bits(score)&~511 | code
    float m1[4], m2[4], m3[4];
    #pragma unroll
    for (int s = 0; s < 4; ++s) { m1[s] = m2[s] = m3[s] = 3.0e38f; }

    #pragma unroll 2
    for (int tt = 0; tt < 32; ++tt) {
        const int row = tt * 16 + p16;                 // row&7 == p16&7
        const bf16x8 ah0 = *(const bf16x8*)&simg[row * 64 + jj0];
        const bf16x8 ah1 = *(const bf16x8*)&simg[row * 64 + jj1];
        const bf16x8 al0 = lob[row * 8 + g];           // chunk0 cols g*8..g*8+7
        const bf16x8 al1 = lob[row * 8 + 4 + g];       // chunk1 cols 32+g*8..
        const f32x4 eq = eqb[tt * 4 + g];              // esqb[tt*16 + g*4 .. +3]
        const unsigned c0 = (unsigned)(tt * 16 + g * 4);

        #pragma unroll
        for (int s = 0; s < 4; ++s) {
            f32x4 acc = {0.f, 0.f, 0.f, 0.f};
            acc = __builtin_amdgcn_mfma_f32_16x16x32_bf16(ah0, zh[s][0], acc, 0, 0, 0);
            acc = __builtin_amdgcn_mfma_f32_16x16x32_bf16(ah1, zh[s][1], acc, 0, 0, 0);
            acc = __builtin_amdgcn_mfma_f32_16x16x32_bf16(al0, zh[s][0], acc, 0, 0, 0);
            acc = __builtin_amdgcn_mfma_f32_16x16x32_bf16(al1, zh[s][1], acc, 0, 0, 0);
            acc = __builtin_amdgcn_mfma_f32_16x16x32_bf16(ah0, zl[s][0], acc, 0, 0, 0);
            acc = __builtin_amdgcn_mfma_f32_16x16x32_bf16(ah1, zl[s][1], acc, 0, 0, 0);
            #pragma unroll
            for (int rr = 0; rr < 4; ++rr) {
                float sc = fmaf(-2.0f, acc[rr], eq[rr]);
                float kf = __uint_as_float(
                    (__float_as_uint(sc) & 0xFFFFFE00u) | (c0 + (unsigned)rr));
                // sorted top-3 insert; med3 valid since m1<=m2<=m3 invariant
                float n1 = fminf(kf, m1[s]);
                float n2 = __builtin_amdgcn_fmed3f(kf, m1[s], m2[s]);
                float n3 = __builtin_amdgcn_fmed3f(kf, m2[s], m3[s]);
                m1[s] = n1; m2[s] = n2; m3[s] = n3;
            }
        }
    }

    // merge the 4 code-partitions (lane groups) per set: butterfly xor 16, 32
    #pragma unroll
    for (int s = 0; s < 4; ++s) {
        #pragma unroll
        for (int st2 = 0; st2 < 2; ++st2) {
            const int mk = 16 << st2;
            float b1 = __shfl_xor(m1[s], mk);
            float b2 = __shfl_xor(m2[s], mk);
            float b3 = __shfl_xor(m3[s], mk);
            float osa = __shfl_xor(sab[s], mk);
            sab[s] += osa;
            float M1 = fminf(m1[s], b1), x = fmaxf(m1[s], b1);
            float c  = fminf(m2[s], b2), d = fmaxf(m2[s], b2);
            float M2 = fminf(x, c),      e2 = fmaxf(x, c);
            float M3 = fminf(fminf(e2, d), fminf(m3[s], b3));
            m1[s] = M1; m2[s] = M2; m3[s] = M3;
        }
    }

    // lane owns pixel (set=g, p16)
    float F1 = (g == 0) ? m1[0] : (g == 1) ? m1[1] : (g == 2) ? m1[2] : m1[3];
    float F2 = (g == 0) ? m2[0] : (g == 1) ? m2[1] : (g == 2) ? m2[2] : m2[3];
    float F3 = (g == 0) ? m3[0] : (g == 1) ? m3[1] : (g == 2) ? m3[2] : m3[3];
    float SA = (g == 0) ? sab[0] : (g == 1) ? sab[1] : (g == 2) ? sab[2] : sab[3];

    const unsigned K1 = __float_as_uint(F1);
    const unsigned K2 = __float_as_uint(F2);
    const unsigned K3 = __float_as_uint(F3);
    const float qs1 = __uint_as_float(K1 & 0xFFFFFE00u);
    const float qs2 = __uint_as_float(K2 & 0xFFFFFE00u);
    const float qs3 = __uint_as_float(K3 & 0xFFFFFE00u);
    const int   I1  = (int)(K1 & 511u);
    const int   I2  = (int)(K2 & 511u);

    // round-4/5/7/8/10-verified sound margin
    const float MARG = 6.0e-5f + 3.0e-5f * (SA * maxe);
    const bool  f2 = (qs2 - qs1) < MARG;
    const bool  f3 = ((qs3 - qs1) < MARG) || (2.f * SA * maxe > 0.45f) || !(qs1 > 0.f);

    const int pix = P0 + w * 64 + lane;
    bool ovf = false;
    if (f3) {
        unsigned i = atomicAdd((unsigned*)(ws + WS_CNTB), 1u);
        if (i < capB) ((unsigned*)(ws + WS_LISTA + 8ull * capA))[i] = (unsigned)pix;
        else ovf = true;
    } else if (f2) {
        unsigned i = atomicAdd((unsigned*)(ws + WS_CNTA), 1u);
        if (i < capA) {
            unsigned a = (unsigned)min(I1, I2), b = (unsigned)max(I1, I2);
            uint2 rec; rec.x = (unsigned)pix; rec.y = (a << 9) | b;
            ((uint2*)(ws + WS_LISTA))[i] = rec;
        } else ovf = true;
    }

    int idx = I1;
    // last-resort inline cooperative rescan (list overflow / caps==0 only)
    unsigned long long bal = __ballot(ovf);
    if (bal) {
        const float* esqr = (const float*)(ws + WS_ESQ);
        while (bal) {
            int pl = __ffsll((long long)bal) - 1;
            bal &= bal - 1;
            const float* zfp = zbase + hwW + pl;
            float bD = 3.0e38f; int bC = 0;
            #pragma unroll
            for (int j = 0; j < 8; ++j) {
                int c = j * 64 + lane;
                float D = np_dist_strided(zfp, emb + c * DDIM, esqr[c]);
                if (D < bD) { bD = D; bC = c; }
            }
            #pragma unroll
            for (int mk = 1; mk < 64; mk <<= 1) {
                float oD = __shfl_xor(bD, mk);
                int   oC = __shfl_xor(bC, mk);
                if (oD < bD || (oD == bD && oC < bC)) { bD = oD; bC = oC; }
            }
            if (lane == pl) idx = bC;
        }
    }
    out[pix] = idx;
}

// ---------------- tail kernel: resolve flagged pixels with bit-exact np semantics ----------------
__global__ __launch_bounds__(256) void vq_tail_kernel(
    const float* __restrict__ z, const float* __restrict__ emb,
    char* __restrict__ ws, int* __restrict__ out, unsigned capA, unsigned capB)
{
    const unsigned nA = umin_(*(const unsigned*)(ws + WS_CNTA), capA);
    const unsigned nB = umin_(*(const unsigned*)(ws + WS_CNTB), capB);
    const float* esqr = (const float*)(ws + WS_ESQ);
    const unsigned gid  = blockIdx.x * 256 + threadIdx.x;
    const unsigned gsz  = gridDim.x * 256;

    // type A: 2-candidate np compare, thread-parallel (a < b -> first-occurrence wins)
    for (unsigned i = gid; i < nA; i += gsz) {
        uint2 rec = ((const uint2*)(ws + WS_LISTA))[i];
        const int pix = (int)rec.x;
        const int a = (int)((rec.y >> 9) & 511u), b = (int)(rec.y & 511u);
        const float* zp = z + (size_t)(pix >> 12) * (DDIM * 4096) + (pix & 4095);
        float Da = np_dist_strided(zp, emb + a * DDIM, esqr[a]);
        float Db = np_dist_strided(zp, emb + b * DDIM, esqr[b]);
        out[pix] = (Db < Da) ? b : a;
    }

    // type B: full 512-code np rescan, wave-cooperative
    const unsigned wid  = gid >> 6;
    const unsigned nwav = gsz >> 6;
    const int lane = threadIdx.x & 63;
    const unsigned* listB = (const unsigned*)(ws + WS_LISTA + 8ull * capA);
    for (unsigned j = wid; j < nB; j += nwav) {
        const int pix = (int)listB[j];
        const float* zp = z + (size_t)(pix >> 12) * (DDIM * 4096) + (pix & 4095);
        float bD = 3.0e38f; int bC = 0;
        #pragma unroll
        for (int q = 0; q < 8; ++q) {
            int c = q * 64 + lane;
            float D = np_dist_strided(zp, emb + c * DDIM, esqr[c]);
            if (D < bD) { bD = D; bC = c; }
        }
        #pragma unroll
        for (int mk = 1; mk < 64; mk <<= 1) {
            float oD = __shfl_xor(bD, mk);
            int   oC = __shfl_xor(bC, mk);
            if (oD < bD || (oD == bD && oC < bC)) { bD = oD; bC = oC; }
        }
        if (lane == 0) out[pix] = bC;
    }
}

// ---------------- fallback (ws too small): round-2 verified self-contained kernel ----------------
__device__ __forceinline__ float fb_fast_score(const float4* __restrict__ e4,
                                               const float* zr, float esqk)
{
    float a0 = 0.f, a1 = 0.f, a2 = 0.f, a3 = 0.f;
    #pragma unroll
    for (int i = 0; i < DDIM / 4; ++i) {
        float4 v = e4[i];
        a0 = fmaf(zr[4*i+0], v.x, a0);
        a1 = fmaf(zr[4*i+1], v.y, a1);
        a2 = fmaf(zr[4*i+2], v.z, a2);
        a3 = fmaf(zr[4*i+3], v.w, a3);
    }
    return fmaf(-2.f, (a0 + a1) + (a2 + a3), esqk);
}

__device__ __forceinline__ float fb_np_dist(const float* __restrict__ e,
                                            const float* zr, float zsq, float esqk)
{
    float c = 0.f;
    #pragma unroll
    for (int d = 0; d < DDIM; ++d)
        c = __fadd_rn(c, __fmul_rn(zr[d], e[d]));
    return __fadd_rn(__fsub_rn(zsq, __fmul_rn(2.0f, c)), esqk);
}

__global__ __launch_bounds__(256) void vq_fallback_kernel(
    const float* __restrict__ z, const float* __restrict__ emb, int* __restrict__ out)
{
    __shared__ float esq[KCODES];
    const int t = threadIdx.x;
    for (int k = t; k < KCODES; k += 256) {
        const float* e = emb + k * DDIM;
        float r[8];
        #pragma unroll
        for (int j = 0; j < 8; ++j) r[j] = __fmul_rn(e[j], e[j]);
        #pragma unroll
        for (int i = 8; i < DDIM; i += 8)
            #pragma unroll
            for (int j = 0; j < 8; ++j)
                r[j] = __fadd_rn(r[j], __fmul_rn(e[i+j], e[i+j]));
        esq[k] = __fadd_rn(
            __fadd_rn(__fadd_rn(r[0], r[1]), __fadd_rn(r[2], r[3])),
            __fadd_rn(__fadd_rn(r[4], r[5]), __fadd_rn(r[6], r[7])));
    }
    __syncthreads();
    const int p  = blockIdx.x * 256 + t;
    const int b  = p >> 12;
    const int hw = p & 4095;
    const float* zp = z + (size_t)b * (DDIM * 4096) + hw;
    float zr[DDIM];
    #pragma unroll
    for (int d = 0; d < DDIM; ++d) zr[d] = zp[(size_t)d * 4096];
    float zsq = __fmul_rn(zr[0], zr[0]);
    #pragma unroll
    for (int d = 1; d < DDIM; ++d)
        zsq = __fadd_rn(zsq, __fmul_rn(zr[d], zr[d]));
    float m1 = 3.0e38f, m2 = 3.0e38f, m3 = 3.0e38f;
    int   i1 = 0, i2 = 0;
    for (int k = 0; k < KCODES; ++k) {
        const float s = fb_fast_score(reinterpret_cast<const float4*>(emb + k * DDIM), zr, esq[k]);
        const bool b1 = s < m1, b2 = s < m2, b3 = s < m3;
        const float nm3 = b2 ? m2 : (b3 ? s : m3);
        const float nm2 = b1 ? m1 : (b2 ? s : m2);
        const int   ni2 = b1 ? i1 : (b2 ? k : i2);
        const float nm1 = b1 ? s : m1;
        const int   ni1 = b1 ? k : i1;
        m3 = nm3; m2 = nm2; i2 = ni2; m1 = nm1; i1 = ni1;
    }
    int idx = i1;
    if (m2 - m1 < 6.0e-5f) {
        if (m3 - m1 >= 6.0e-5f) {
            const float D1 = fb_np_dist(emb + i1 * DDIM, zr, zsq, esq[i1]);
            const float D2 = fb_np_dist(emb + i2 * DDIM, zr, zsq, esq[i2]);
            const int   ka = (i1 < i2) ? i1 : i2;
            const int   kb = (i1 < i2) ? i2 : i1;
            const float Da = (i1 < i2) ? D1 : D2;
            const float Db = (i1 < i2) ? D2 : D1;
            idx = (Db < Da) ? kb : ka;
        } else {
            float bestD = 3.0e38f; int bi = 0; bool found = false;
            for (int k = 0; k < KCODES; ++k) {
                const float s = fb_fast_score(reinterpret_cast<const float4*>(emb + k * DDIM), zr, esq[k]);
                if (s < m1 + 6.0e-5f) {
                    const float Dk = fb_np_dist(emb + k * DDIM, zr, zsq, esq[k]);
                    if (!found || Dk < bestD) { bestD = Dk; bi = k; found = true; }
                }
            }
            idx = bi;
        }
    }
    out[p] = idx;
}

extern "C" void kernel_launch(void* const* d_in, const int* in_sizes, int n_in,
                              void* d_out, int out_size, void* d_ws, size_t ws_size,
                              hipStream_t stream)
{
    const float* z   = (const float*)d_in[0];
    const float* emb = (const float*)d_in[1];
    int* out = (int*)d_out;

    // pick list capacities from available workspace
    unsigned capA = 0, capB = 0;
    if (ws_size >= (size_t)WS_LISTA + 32768ull * 8 + 8192ull * 4)      { capA = 32768; capB = 8192; }
    else if (ws_size >= (size_t)WS_LISTA + 16384ull * 8 + 4096ull * 4) { capA = 16384; capB = 4096; }

    if (ws_size >= (size_t)WS_LISTA && (out_size % 512) == 0) {
        hipLaunchKernelGGL(vq_pre_kernel, dim3(8), dim3(64), 0, stream, emb, (char*)d_ws);
        hipLaunchKernelGGL(vq_main_kernel, dim3(out_size / 512), dim3(512), 0, stream,
                           z, emb, (char*)d_ws, out, capA, capB);
        if (capA > 0)
            hipLaunchKernelGGL(vq_tail_kernel, dim3(128), dim3(256), 0, stream,
                               z, emb, (char*)d_ws, out, capA, capB);
    } else {
        hipLaunchKernelGGL(vq_fallback_kernel, dim3((out_size + 255) / 256), dim3(256), 0, stream,
                           z, emb, out);
    }
}